// Round 14
// baseline (3524.224 us; speedup 1.0000x reference)
//
#include <hip/hip_runtime.h>
#include <hip/hip_bf16.h>
#include <math.h>

#define D 128
#define NH 8
#define HD 16
#define NL 3
#define DFF 2048
#define NNODE 100
#define BATCH 512
#define M_TOT (BATCH * NNODE) /* 51200 */
#define LN_EPS 1e-5f
// bf16-finite sentinel (reference's -3.4e38 is -inf in the bf16 compare).
#define NEGW (-3.0e+38f)

typedef __attribute__((ext_vector_type(8))) short bf16x8;
typedef __attribute__((ext_vector_type(4))) float f32x4;

__device__ __forceinline__ unsigned short f2bf(float x) {
  unsigned u = __float_as_uint(x);
  u = u + 0x7FFFu + ((u >> 16) & 1u);  // RNE
  return (unsigned short)(u >> 16);
}
__device__ __forceinline__ float bf2f(unsigned short s) {
  return __uint_as_float(((unsigned)s) << 16);
}

// ---------------- split fp32 -> bf16 hi/lo ----------------
__global__ __launch_bounds__(256) void k_split(
    const float* __restrict__ src, unsigned short* __restrict__ hi,
    unsigned short* __restrict__ lo, int n) {
  int i = blockIdx.x * 256 + threadIdx.x;
  if (i >= n) return;
  float x = src[i];
  unsigned short h = f2bf(x);
  hi[i] = h;
  lo[i] = f2bf(x - bf2f(h));
}

// ---------------- input projection (+ split) ----------------
__global__ __launch_bounds__(256) void k_inproj(
    const float* __restrict__ c, const float* __restrict__ w,
    const float* __restrict__ b, float* __restrict__ h,
    unsigned short* __restrict__ hhi, unsigned short* __restrict__ hlo) {
  int idx = blockIdx.x * 256 + threadIdx.x;
  if (idx >= M_TOT * D) return;
  int m = idx >> 7, d = idx & 127;
  float v = c[m * 2] * w[d * 2] + c[m * 2 + 1] * w[d * 2 + 1] + b[d];
  h[idx] = v;
  unsigned short t = f2bf(v);
  hhi[idx] = t;
  hlo[idx] = f2bf(v - bf2f(t));
}

// ---- bf16x3 MFMA GEMM, fragments DIRECT FROM GLOBAL (no LDS, no barriers) ----
// Every A/W byte feeds exactly one lane's fragment, so LDS staging added no
// sharing — removed. A rows clamped to M-1 (tail-safe); N%128==0, K%32==0.
__global__ __launch_bounds__(256) void k_gemm3(
    const unsigned short* __restrict__ Ah, const unsigned short* __restrict__ Al,
    const unsigned short* __restrict__ Wh, const unsigned short* __restrict__ Wl,
    const float* __restrict__ bias,
    float* __restrict__ C, unsigned short* __restrict__ Chi,
    unsigned short* __restrict__ Clo, int M, int N, int K, int relu_split) {
  const int m0 = blockIdx.x * 64, n0 = blockIdx.y * 128;
  const int tid = threadIdx.x, lane = tid & 63, wid = tid >> 6;
  const int wr = wid >> 1, wc = wid & 1;
  const int lr = lane & 15, lg = lane >> 4;
  f32x4 acc[2][4];
#pragma unroll
  for (int a = 0; a < 2; ++a)
#pragma unroll
    for (int b = 0; b < 4; ++b) acc[a][b] = (f32x4){0.f, 0.f, 0.f, 0.f};
  long long arow[2], wrow[4];
#pragma unroll
  for (int fm = 0; fm < 2; ++fm) {
    int r = m0 + wr * 32 + fm * 16 + lr;
    if (r > M - 1) r = M - 1;
    arow[fm] = (long long)r * K + lg * 8;
  }
#pragma unroll
  for (int fn = 0; fn < 4; ++fn)
    wrow[fn] = (long long)(n0 + wc * 64 + fn * 16 + lr) * K + lg * 8;
#pragma unroll 2
  for (int k0 = 0; k0 < K; k0 += 32) {
    bf16x8 fah[2], fal[2], fwh[4], fwl[4];
#pragma unroll
    for (int fm = 0; fm < 2; ++fm) {
      fah[fm] = *(const bf16x8*)(Ah + arow[fm] + k0);
      fal[fm] = *(const bf16x8*)(Al + arow[fm] + k0);
    }
#pragma unroll
    for (int fn = 0; fn < 4; ++fn) {
      fwh[fn] = *(const bf16x8*)(Wh + wrow[fn] + k0);
      fwl[fn] = *(const bf16x8*)(Wl + wrow[fn] + k0);
    }
#pragma unroll
    for (int fm = 0; fm < 2; ++fm)
#pragma unroll
      for (int fn = 0; fn < 4; ++fn) {
        acc[fm][fn] = __builtin_amdgcn_mfma_f32_16x16x32_bf16(
            fah[fm], fwl[fn], acc[fm][fn], 0, 0, 0);
        acc[fm][fn] = __builtin_amdgcn_mfma_f32_16x16x32_bf16(
            fal[fm], fwh[fn], acc[fm][fn], 0, 0, 0);
        acc[fm][fn] = __builtin_amdgcn_mfma_f32_16x16x32_bf16(
            fah[fm], fwh[fn], acc[fm][fn], 0, 0, 0);
      }
  }
#pragma unroll
  for (int fm = 0; fm < 2; ++fm) {
    int rb = m0 + wr * 32 + fm * 16 + lg * 4;
#pragma unroll
    for (int fn = 0; fn < 4; ++fn) {
      int col = n0 + wc * 64 + fn * 16 + lr;
      float bv = bias[col];
#pragma unroll
      for (int j = 0; j < 4; ++j) {
        int row = rb + j;
        if (row < M) {
          float v = acc[fm][fn][j] + bv;
          if (relu_split) {
            v = fmaxf(v, 0.f);
            unsigned short hv = f2bf(v);
            long long o = (long long)row * N + col;
            Chi[o] = hv;
            Clo[o] = f2bf(v - bf2f(hv));
          } else {
            C[(long long)row * N + col] = v;
          }
        }
      }
    }
  }
}

// ---- same direct-global GEMM with FUSED residual + LayerNorm + split (N=128) ----
__global__ __launch_bounds__(256) void k_gemm3_ln(
    const unsigned short* __restrict__ Ah, const unsigned short* __restrict__ Al,
    const unsigned short* __restrict__ Wh, const unsigned short* __restrict__ Wl,
    const float* __restrict__ bias, const float* __restrict__ g,
    const float* __restrict__ be, float* __restrict__ hres,
    unsigned short* __restrict__ hhi, unsigned short* __restrict__ hlo,
    int M, int K) {
  __shared__ float redS[64][2];
  __shared__ float redQ[64][2];
  const int m0 = blockIdx.x * 64;
  const int tid = threadIdx.x, lane = tid & 63, wid = tid >> 6;
  const int wr = wid >> 1, wc = wid & 1;
  const int lr = lane & 15, lg = lane >> 4;
  f32x4 acc[2][4];
#pragma unroll
  for (int a = 0; a < 2; ++a)
#pragma unroll
    for (int b = 0; b < 4; ++b) acc[a][b] = (f32x4){0.f, 0.f, 0.f, 0.f};
  long long arow[2], wrow[4];
#pragma unroll
  for (int fm = 0; fm < 2; ++fm) {
    int r = m0 + wr * 32 + fm * 16 + lr;
    if (r > M - 1) r = M - 1;
    arow[fm] = (long long)r * K + lg * 8;
  }
#pragma unroll
  for (int fn = 0; fn < 4; ++fn)
    wrow[fn] = (long long)(wc * 64 + fn * 16 + lr) * K + lg * 8;
#pragma unroll 2
  for (int k0 = 0; k0 < K; k0 += 32) {
    bf16x8 fah[2], fal[2], fwh[4], fwl[4];
#pragma unroll
    for (int fm = 0; fm < 2; ++fm) {
      fah[fm] = *(const bf16x8*)(Ah + arow[fm] + k0);
      fal[fm] = *(const bf16x8*)(Al + arow[fm] + k0);
    }
#pragma unroll
    for (int fn = 0; fn < 4; ++fn) {
      fwh[fn] = *(const bf16x8*)(Wh + wrow[fn] + k0);
      fwl[fn] = *(const bf16x8*)(Wl + wrow[fn] + k0);
    }
#pragma unroll
    for (int fm = 0; fm < 2; ++fm)
#pragma unroll
      for (int fn = 0; fn < 4; ++fn) {
        acc[fm][fn] = __builtin_amdgcn_mfma_f32_16x16x32_bf16(
            fah[fm], fwl[fn], acc[fm][fn], 0, 0, 0);
        acc[fm][fn] = __builtin_amdgcn_mfma_f32_16x16x32_bf16(
            fal[fm], fwh[fn], acc[fm][fn], 0, 0, 0);
        acc[fm][fn] = __builtin_amdgcn_mfma_f32_16x16x32_bf16(
            fah[fm], fwh[fn], acc[fm][fn], 0, 0, 0);
      }
  }
  // ---- fused epilogue: x = residual + gemm + bias; row LN over 128 cols ----
  float x[2][4][4];
#pragma unroll
  for (int fm = 0; fm < 2; ++fm)
#pragma unroll
    for (int fn = 0; fn < 4; ++fn) {
      int col = wc * 64 + fn * 16 + lr;
      float bv = bias[col];
#pragma unroll
      for (int j = 0; j < 4; ++j) {
        int row = m0 + wr * 32 + fm * 16 + lg * 4 + j;
        float r = (row < M) ? hres[(long long)row * D + col] : 0.f;
        x[fm][fn][j] = acc[fm][fn][j] + bv + r;
      }
    }
#pragma unroll
  for (int fm = 0; fm < 2; ++fm)
#pragma unroll
    for (int j = 0; j < 4; ++j) {
      float s = x[fm][0][j] + x[fm][1][j] + x[fm][2][j] + x[fm][3][j];
      s += __shfl_xor(s, 1);
      s += __shfl_xor(s, 2);
      s += __shfl_xor(s, 4);
      s += __shfl_xor(s, 8);
      if (lr == 0) redS[wr * 32 + fm * 16 + lg * 4 + j][wc] = s;
    }
  __syncthreads();
  float mean[2][4];
#pragma unroll
  for (int fm = 0; fm < 2; ++fm)
#pragma unroll
    for (int j = 0; j < 4; ++j) {
      int rl = wr * 32 + fm * 16 + lg * 4 + j;
      mean[fm][j] = (redS[rl][0] + redS[rl][1]) * (1.f / 128.f);
      float d0 = x[fm][0][j] - mean[fm][j];
      float d1 = x[fm][1][j] - mean[fm][j];
      float d2 = x[fm][2][j] - mean[fm][j];
      float d3 = x[fm][3][j] - mean[fm][j];
      float q = d0 * d0 + d1 * d1 + d2 * d2 + d3 * d3;
      q += __shfl_xor(q, 1);
      q += __shfl_xor(q, 2);
      q += __shfl_xor(q, 4);
      q += __shfl_xor(q, 8);
      if (lr == 0) redQ[rl][wc] = q;
    }
  __syncthreads();
#pragma unroll
  for (int fm = 0; fm < 2; ++fm)
#pragma unroll
    for (int j = 0; j < 4; ++j) {
      int rl = wr * 32 + fm * 16 + lg * 4 + j;
      int row = m0 + rl;
      if (row >= M) continue;
      float var = (redQ[rl][0] + redQ[rl][1]) * (1.f / 128.f);
      float sd = sqrtf(var + LN_EPS);
#pragma unroll
      for (int fn = 0; fn < 4; ++fn) {
        int col = wc * 64 + fn * 16 + lr;
        float o = (x[fm][fn][j] - mean[fm][j]) / sd * g[col] + be[col];
        long long ix = (long long)row * D + col;
        hres[ix] = o;
        unsigned short t = f2bf(o);
        hhi[ix] = t;
        hlo[ix] = f2bf(o - bf2f(t));
      }
    }
}

// ---- fp32 vector GEMM (batched S = q@k^T, N=100) ----
__global__ __launch_bounds__(256) void k_gemm(
    const float* __restrict__ A, long long sA,
    const float* __restrict__ W, long long sW,
    const float* __restrict__ bias,
    float* __restrict__ C, long long sC,
    int M, int N, int K, float scale, int relu) {
  __shared__ float As[32][72];
  __shared__ float Ws[32][72];
  A += (long long)blockIdx.z * sA;
  W += (long long)blockIdx.z * sW;
  C += (long long)blockIdx.z * sC;
  int m0 = blockIdx.x * 64, n0 = blockIdx.y * 64;
  int tid = threadIdx.x;
  int lx = tid & 31, ly = tid >> 5;
  int tc = tid & 15, tr = tid >> 4;
  float acc[4][4] = {};
  for (int k0 = 0; k0 < K; k0 += 32) {
#pragma unroll
    for (int i = 0; i < 8; ++i) {
      int m = m0 + ly + i * 8;
      As[lx][ly + i * 8] = (m < M) ? A[(long long)m * K + k0 + lx] : 0.f;
      int n = n0 + ly + i * 8;
      Ws[lx][ly + i * 8] = (n < N) ? W[(long long)n * K + k0 + lx] : 0.f;
    }
    __syncthreads();
#pragma unroll
    for (int k = 0; k < 32; ++k) {
      float4 av = *(const float4*)&As[k][tr * 4];
      float4 wv = *(const float4*)&Ws[k][tc * 4];
      const float* ap = (const float*)&av;
      const float* wp = (const float*)&wv;
#pragma unroll
      for (int i = 0; i < 4; ++i)
#pragma unroll
        for (int j = 0; j < 4; ++j)
          acc[i][j] = fmaf(ap[i], wp[j], acc[i][j]);
    }
    __syncthreads();
  }
#pragma unroll
  for (int i = 0; i < 4; ++i) {
    int m = m0 + tr * 4 + i;
    if (m >= M) continue;
#pragma unroll
    for (int j = 0; j < 4; ++j) {
      int n = n0 + tc * 4 + j;
      if (n >= N) continue;
      float v = acc[i][j] * scale;
      if (bias) v += bias[n];
      if (relu) v = fmaxf(v, 0.f);
      C[(long long)m * N + n] = v;
    }
  }
}

// ---------------- attention: 512 thr; swizzled K (kills 8-way conflict);
// float4 PV ----
__global__ __launch_bounds__(512) void k_attn(
    const float* __restrict__ qkv, unsigned short* __restrict__ aoh,
    unsigned short* __restrict__ aol) {
  __shared__ float Qs[NNODE][20];  // linear; reused as softmax scratch
  __shared__ float Ks[NNODE][20];  // block-rotated by (j>>3)&3
  __shared__ float Vs[NNODE][20];  // linear (PV reads are same-k broadcast)
  __shared__ float Ss[NNODE][101];
  int bh = blockIdx.x;
  int b = bh >> 3, hh = bh & 7;
  const float* base = qkv + (long long)b * NNODE * 384 + hh * HD;
  int tid = threadIdx.x;
  for (int idx = tid; idx < NNODE * HD; idx += 512) {
    int n = idx >> 4, d2 = idx & 15;
    float qv = base[(long long)n * 384 + d2];
    float kv = base[(long long)n * 384 + 128 + d2];
    float vv = base[(long long)n * 384 + 256 + d2];
    Qs[n][d2] = qv;
    // K swizzle: logical float4-block (d2>>2) stored at ((d2>>2)+(n>>3))&3
    int kp = ((((d2 >> 2) + (n >> 3)) & 3) << 2) | (d2 & 3);
    Ks[n][kp] = kv;
    Vs[n][d2] = vv;
  }
  __syncthreads();
  for (int p = tid; p < NNODE * NNODE; p += 512) {
    int i = p / 100, j = p - i * 100;
    int rot = (j >> 3) & 3;
    const float4* qv = (const float4*)&Qs[i][0];
    float s = 0.f;
#pragma unroll
    for (int t = 0; t < 4; ++t) {
      float4 q = qv[t];
      float4 k = *(const float4*)&Ks[j][(((t + rot) & 3) << 2)];
      s = fmaf(q.x, k.x, s);
      s = fmaf(q.y, k.y, s);
      s = fmaf(q.z, k.z, s);
      s = fmaf(q.w, k.w, s);
    }
    Ss[i][j] = s * 0.25f; /* hd^-0.5 */
  }
  __syncthreads();
  // parallel softmax: 2 threads/row (Qs dead -> scratch)
  float* red = (float*)Qs;
  int r = tid >> 1, hf = tid & 1;
  float* row = &Ss[r][hf * 50];
  if (tid < 200) {
    float mx = row[0];
    for (int j = 1; j < 50; ++j) mx = fmaxf(mx, row[j]);
    red[tid] = mx;
  }
  __syncthreads();
  if (tid < 200) {
    float mx = fmaxf(red[r * 2], red[r * 2 + 1]);
    float sum = 0.f;
    for (int j = 0; j < 50; ++j) {
      float e = expf(row[j] - mx);
      row[j] = e;
      sum += e;
    }
    red[256 + tid] = sum;
  }
  __syncthreads();
  if (tid < 200) {
    float tot = red[256 + r * 2] + red[256 + r * 2 + 1];
    for (int j = 0; j < 50; ++j) row[j] = row[j] / tot;
  }
  __syncthreads();
  // PV: one float4 of V per thread-output (100 rows x 4 quads = 400 tasks)
  for (int p = tid; p < NNODE * 4; p += 512) {
    int i = p >> 2, q = p & 3;
    float4 o = {0.f, 0.f, 0.f, 0.f};
    for (int k = 0; k < NNODE; ++k) {
      float sv = Ss[i][k];
      float4 v = *(const float4*)&Vs[k][q << 2];
      o.x = fmaf(sv, v.x, o.x);
      o.y = fmaf(sv, v.y, o.y);
      o.z = fmaf(sv, v.z, o.z);
      o.w = fmaf(sv, v.w, o.w);
    }
    long long idx = ((long long)b * NNODE + i) * D + hh * HD + (q << 2);
    const float* op = (const float*)&o;
#pragma unroll
    for (int e = 0; e < 4; ++e) {
      unsigned short hv = f2bf(op[e]);
      aoh[idx + e] = hv;
      aol[idx + e] = f2bf(op[e] - bf2f(hv));
    }
  }
}

// ---------------- greedy decode: one wave per batch element ----------------
__global__ __launch_bounds__(64) void k_decode(
    const float* __restrict__ S, const int* __restrict__ start,
    float* __restrict__ tour, float* __restrict__ logits) {
  __shared__ float Sl[NNODE * NNODE];
  int b = blockIdx.x;
  const float* Sg = S + (long long)b * NNODE * NNODE;
  int l = threadIdx.x;
  for (int i = l; i < NNODE * NNODE; i += 64) Sl[i] = Sg[i];
  __syncthreads();
  unsigned long long visLo = 1ull, visHi = 0ull;
  int node = start[b];
  float* lg = logits + (long long)b * 99 * 100;
  for (int t = 0; t < 99; ++t) {
    if (node < 64) visLo |= 1ull << node;
    else visHi |= 1ull << (node - 64);
    const float* row = &Sl[node * 100];
    float c0 = ((visLo >> l) & 1ull) ? NEGW : row[l];
    float c1 = NEGW;
    int j2 = l + 64;
    if (j2 < NNODE && !((visHi >> l) & 1ull)) c1 = row[j2];
    lg[t * 100 + l] = c0;
    if (j2 < NNODE) lg[t * 100 + j2] = c1;
    if (l == 0) tour[b * 99 + t] = (float)node;
    float v = c0;
    int idx = l;
    if (c1 > v) { v = c1; idx = j2; }
    for (int off = 32; off; off >>= 1) {
      float ov = __shfl_xor(v, off);
      int oi = __shfl_xor(idx, off);
      if (ov > v || (ov == v && oi < idx)) { v = ov; idx = oi; }
    }
    node = idx;
  }
}

extern "C" void kernel_launch(void* const* d_in, const int* in_sizes, int n_in,
                              void* d_out, int out_size, void* d_ws, size_t ws_size,
                              hipStream_t stream) {
  const float* c     = (const float*)d_in[0];
  const int*   start = (const int*)d_in[1];
  const float* w_inp = (const float*)d_in[2];
  const float* b_inp = (const float*)d_in[3];
  const float* wqkv  = (const float*)d_in[4];
  const float* bqkv  = (const float*)d_in[5];
  const float* wo    = (const float*)d_in[6];
  const float* bo    = (const float*)d_in[7];
  const float* w1    = (const float*)d_in[8];
  const float* b1    = (const float*)d_in[9];
  const float* w2    = (const float*)d_in[10];
  const float* b2    = (const float*)d_in[11];
  const float* g1    = (const float*)d_in[12];
  const float* be1   = (const float*)d_in[13];
  const float* g2    = (const float*)d_in[14];
  const float* be2   = (const float*)d_in[15];
  const float* wq    = (const float*)d_in[16];
  const float* bq    = (const float*)d_in[17];
  const float* wk    = (const float*)d_in[18];
  const float* bk    = (const float*)d_in[19];

  // ---- workspace layout (validated R10/R11) ----
  float* h = (float*)d_ws;
  unsigned short* h_hi = (unsigned short*)((char*)d_ws + 26214400);
  unsigned short* h_lo = h_hi + (size_t)M_TOT * D;
  unsigned short* wsp  = (unsigned short*)((char*)d_ws + 52428800);
  unsigned short* wqkvh = wsp;
  unsigned short* wqkvl = wsp + 147456;
  unsigned short* woh   = wsp + 294912;
  unsigned short* wol   = wsp + 344064;
  unsigned short* w1h   = wsp + 393216;
  unsigned short* w1l   = wsp + 1179648;
  unsigned short* w2h   = wsp + 1966080;
  unsigned short* w2l   = wsp + 2752512;
  unsigned short* wqh   = wsp + 3538944;
  unsigned short* wql   = wsp + 3555328;
  unsigned short* wkh   = wsp + 3571712;
  unsigned short* wkl   = wsp + 3588096;
  float* wsArena = (float*)((char*)d_ws + 59637760);
  long long R = (long long)ws_size - 59637760LL;
  if (R < 0) R = 0;

  float* tour   = (float*)d_out;
  float* logits = (float*)d_out + (size_t)BATCH * (NNODE - 1);
  long long LBYTES = (long long)BATCH * (NNODE - 1) * NNODE * 4;

  float* encArena = (R >= LBYTES) ? wsArena : logits;
  long long E = (R >= LBYTES) ? R : LBYTES;

  long long CB = E / 204800;
  if (CB < 1) CB = 1;
  if (CB > BATCH) CB = BATCH;
  long long RB = (E / 8192) & ~3LL;
  if (RB < 4) RB = 4;
  if (RB > M_TOT) RB = M_TOT;
  long long CB2 = R / 142400;
  if (CB2 < 1) CB2 = 1;
  if (CB2 > BATCH) CB2 = BATCH;

  k_split<<<576, 256, 0, stream>>>(wqkv, wqkvh, wqkvl, 147456);
  k_split<<<192, 256, 0, stream>>>(wo, woh, wol, 49152);
  k_split<<<3072, 256, 0, stream>>>(w1, w1h, w1l, 786432);
  k_split<<<3072, 256, 0, stream>>>(w2, w2h, w2l, 786432);
  k_split<<<64, 256, 0, stream>>>(wq, wqh, wql, 16384);
  k_split<<<64, 256, 0, stream>>>(wk, wkh, wkl, 16384);

  k_inproj<<<(M_TOT * D + 255) / 256, 256, 0, stream>>>(c, w_inp, b_inp, h,
                                                        h_hi, h_lo);

  for (int l = 0; l < NL; ++l) {
    unsigned short* wqkvh_l = wqkvh + (size_t)l * 49152;
    unsigned short* wqkvl_l = wqkvl + (size_t)l * 49152;
    unsigned short* woh_l = woh + (size_t)l * 16384;
    unsigned short* wol_l = wol + (size_t)l * 16384;
    unsigned short* w1h_l = w1h + (size_t)l * 262144;
    unsigned short* w1l_l = w1l + (size_t)l * 262144;
    unsigned short* w2h_l = w2h + (size_t)l * 262144;
    unsigned short* w2l_l = w2l + (size_t)l * 262144;
    const float* bqkv_l = bqkv + (size_t)l * 384;
    const float* bo_l = bo + (size_t)l * D;
    const float* b1_l = b1 + (size_t)l * DFF;
    const float* b2_l = b2 + (size_t)l * D;
    const float* g1_l = g1 + (size_t)l * D;
    const float* be1_l = be1 + (size_t)l * D;
    const float* g2_l = g2 + (size_t)l * D;
    const float* be2_l = be2 + (size_t)l * D;

    // ---- attention sublayer (wo-GEMM + residual + LN1 fused) ----
    for (long long b0 = 0; b0 < BATCH; b0 += CB) {
      long long cb = (BATCH - b0 < CB) ? (BATCH - b0) : CB;
      long long rows = cb * NNODE;
      float* qkvbuf = encArena;
      unsigned short* aoh = (unsigned short*)(qkvbuf + rows * 384);
      unsigned short* aol = aoh + rows * D;
      float* hrow = h + b0 * NNODE * D;
      unsigned short* hhir = h_hi + b0 * NNODE * D;
      unsigned short* hlor = h_lo + b0 * NNODE * D;
      k_gemm3<<<dim3((unsigned)((rows + 63) / 64), 3), 256, 0, stream>>>(
          hhir, hlor, wqkvh_l, wqkvl_l, bqkv_l, qkvbuf, nullptr, nullptr,
          (int)rows, 384, D, 0);
      k_attn<<<(unsigned)(cb * NH), 512, 0, stream>>>(qkvbuf, aoh, aol);
      k_gemm3_ln<<<(unsigned)((rows + 63) / 64), 256, 0, stream>>>(
          aoh, aol, woh_l, wol_l, bo_l, g1_l, be1_l, hrow, hhir, hlor,
          (int)rows, D);
    }

    // ---- FFN sublayer (w2-GEMM + residual + LN2 fused) ----
    for (long long r0 = 0; r0 < M_TOT; r0 += RB) {
      long long mr = (M_TOT - r0 < RB) ? (M_TOT - r0) : RB;
      unsigned short* ff1h = (unsigned short*)encArena;
      unsigned short* ff1l = ff1h + mr * DFF;
      float* hrow = h + r0 * D;
      unsigned short* hhir = h_hi + r0 * D;
      unsigned short* hlor = h_lo + r0 * D;
      k_gemm3<<<dim3((unsigned)((mr + 63) / 64), DFF / 128), 256, 0, stream>>>(
          hhir, hlor, w1h_l, w1l_l, b1_l, nullptr, ff1h, ff1l,
          (int)mr, DFF, D, 1);
      k_gemm3_ln<<<(unsigned)((mr + 63) / 64), 256, 0, stream>>>(
          ff1h, ff1l, w2h_l, w2l_l, b2_l, g2_l, be2_l, hrow, hhir, hlor,
          (int)mr, DFF);
    }
  }

  // ---- decode: qp/kp (bf16x3) -> S (fp32) -> greedy ----
  for (long long b0 = 0; b0 < BATCH; b0 += CB2) {
    long long cb = (BATCH - b0 < CB2) ? (BATCH - b0) : CB2;
    long long rows = cb * NNODE;
    float* qp = wsArena;
    float* kp = qp + rows * D;
    float* Sb = kp + rows * D;
    unsigned short* hhir = h_hi + b0 * NNODE * D;
    unsigned short* hlor = h_lo + b0 * NNODE * D;
    k_gemm3<<<dim3((unsigned)((rows + 63) / 64), 1), 256, 0, stream>>>(
        hhir, hlor, wqh, wql, bq, qp, nullptr, nullptr, (int)rows, D, D, 0);
    k_gemm3<<<dim3((unsigned)((rows + 63) / 64), 1), 256, 0, stream>>>(
        hhir, hlor, wkh, wkl, bk, kp, nullptr, nullptr, (int)rows, D, D, 0);
    k_gemm<<<dim3(2, 2, (unsigned)cb), 256, 0, stream>>>(
        qp, (long long)NNODE * D, kp, (long long)NNODE * D, nullptr,
        Sb, (long long)NNODE * NNODE, NNODE, NNODE, D,
        0.08838834764831845f, 0);
    k_decode<<<(unsigned)cb, 64, 0, stream>>>(Sb, start + b0, tour + b0 * 99,
                                              logits + b0 * 99 * 100);
  }
}

// Round 16
// 2263.091 us; speedup vs baseline: 1.5573x; 1.5573x over previous
//
#include <hip/hip_runtime.h>
#include <hip/hip_bf16.h>
#include <math.h>

#define D 128
#define NH 8
#define HD 16
#define NL 3
#define DFF 2048
#define NNODE 100
#define BATCH 512
#define M_TOT (BATCH * NNODE) /* 51200 */
#define LN_EPS 1e-5f
// bf16-finite sentinel (reference's -3.4e38 is -inf in the bf16 compare).
#define NEGW (-3.0e+38f)

typedef __attribute__((ext_vector_type(8))) short bf16x8;
typedef __attribute__((ext_vector_type(4))) float f32x4;
typedef __attribute__((ext_vector_type(8))) unsigned short u16x8;

__device__ __forceinline__ unsigned short f2bf(float x) {
  unsigned u = __float_as_uint(x);
  u = u + 0x7FFFu + ((u >> 16) & 1u);  // RNE
  return (unsigned short)(u >> 16);
}
__device__ __forceinline__ float bf2f(unsigned short s) {
  return __uint_as_float(((unsigned)s) << 16);
}

// ---------------- split fp32 -> bf16 hi/lo ----------------
__global__ __launch_bounds__(256) void k_split(
    const float* __restrict__ src, unsigned short* __restrict__ hi,
    unsigned short* __restrict__ lo, int n) {
  int i = blockIdx.x * 256 + threadIdx.x;
  if (i >= n) return;
  float x = src[i];
  unsigned short h = f2bf(x);
  hi[i] = h;
  lo[i] = f2bf(x - bf2f(h));
}

// ---------------- input projection (+ split) ----------------
__global__ __launch_bounds__(256) void k_inproj(
    const float* __restrict__ c, const float* __restrict__ w,
    const float* __restrict__ b, float* __restrict__ h,
    unsigned short* __restrict__ hhi, unsigned short* __restrict__ hlo) {
  int idx = blockIdx.x * 256 + threadIdx.x;
  if (idx >= M_TOT * D) return;
  int m = idx >> 7, d = idx & 127;
  float v = c[m * 2] * w[d * 2] + c[m * 2 + 1] * w[d * 2 + 1] + b[d];
  h[idx] = v;
  unsigned short t = f2bf(v);
  hhi[idx] = t;
  hlo[idx] = f2bf(v - bf2f(t));
}

// ---- bf16x3 split-precision MFMA GEMM (LDS-staged, R11-validated form) ----
// BM=64, BN=128, BK=32; 256 thr = 4 waves (2x2); wave tile 32x64.
// relu_split=1: relu then write bf16 hi/lo pair; else fp32 C.
__global__ __launch_bounds__(256) void k_gemm3(
    const unsigned short* __restrict__ Ah, const unsigned short* __restrict__ Al,
    const unsigned short* __restrict__ Wh, const unsigned short* __restrict__ Wl,
    const float* __restrict__ bias,
    float* __restrict__ C, unsigned short* __restrict__ Chi,
    unsigned short* __restrict__ Clo, int M, int N, int K, int relu_split) {
  __shared__ unsigned short sAh[64 * 40], sAl[64 * 40];   // pitch 40 shorts = 80B
  __shared__ unsigned short sWh[128 * 40], sWl[128 * 40];
  const int m0 = blockIdx.x * 64, n0 = blockIdx.y * 128;
  const int tid = threadIdx.x, lane = tid & 63, wid = tid >> 6;
  const int wr = wid >> 1, wc = wid & 1;
  const int lr = lane & 15, lg = lane >> 4;
  f32x4 acc[2][4];
#pragma unroll
  for (int a = 0; a < 2; ++a)
#pragma unroll
    for (int b = 0; b < 4; ++b) acc[a][b] = (f32x4){0.f, 0.f, 0.f, 0.f};
  const int ar = tid >> 2, ak = (tid & 3) * 8;
  const int wrr = tid >> 1, wkk = (tid & 1) * 16;
  const bool a_ok = (m0 + ar) < M;
  const long long a_base = (long long)(m0 + ar) * K + ak;
  const long long w_base = (long long)(n0 + wrr) * K + wkk;
  for (int k0 = 0; k0 < K; k0 += 32) {
    u16x8 vah = {0, 0, 0, 0, 0, 0, 0, 0}, val = {0, 0, 0, 0, 0, 0, 0, 0};
    if (a_ok) {
      vah = *(const u16x8*)(Ah + a_base + k0);
      val = *(const u16x8*)(Al + a_base + k0);
    }
    u16x8 vwh0 = *(const u16x8*)(Wh + w_base + k0);
    u16x8 vwh1 = *(const u16x8*)(Wh + w_base + k0 + 8);
    u16x8 vwl0 = *(const u16x8*)(Wl + w_base + k0);
    u16x8 vwl1 = *(const u16x8*)(Wl + w_base + k0 + 8);
    __syncthreads();
    *(u16x8*)&sAh[ar * 40 + ak] = vah;
    *(u16x8*)&sAl[ar * 40 + ak] = val;
    *(u16x8*)&sWh[wrr * 40 + wkk] = vwh0;
    *(u16x8*)&sWh[wrr * 40 + wkk + 8] = vwh1;
    *(u16x8*)&sWl[wrr * 40 + wkk] = vwl0;
    *(u16x8*)&sWl[wrr * 40 + wkk + 8] = vwl1;
    __syncthreads();
    bf16x8 fah[2], fal[2], fwh[4], fwl[4];
#pragma unroll
    for (int fm = 0; fm < 2; ++fm) {
      int o = (wr * 32 + fm * 16 + lr) * 40 + lg * 8;
      fah[fm] = *(const bf16x8*)&sAh[o];
      fal[fm] = *(const bf16x8*)&sAl[o];
    }
#pragma unroll
    for (int fn = 0; fn < 4; ++fn) {
      int o = (wc * 64 + fn * 16 + lr) * 40 + lg * 8;
      fwh[fn] = *(const bf16x8*)&sWh[o];
      fwl[fn] = *(const bf16x8*)&sWl[o];
    }
#pragma unroll
    for (int fm = 0; fm < 2; ++fm)
#pragma unroll
      for (int fn = 0; fn < 4; ++fn) {
        acc[fm][fn] = __builtin_amdgcn_mfma_f32_16x16x32_bf16(
            fah[fm], fwl[fn], acc[fm][fn], 0, 0, 0);
        acc[fm][fn] = __builtin_amdgcn_mfma_f32_16x16x32_bf16(
            fal[fm], fwh[fn], acc[fm][fn], 0, 0, 0);
        acc[fm][fn] = __builtin_amdgcn_mfma_f32_16x16x32_bf16(
            fah[fm], fwh[fn], acc[fm][fn], 0, 0, 0);
      }
  }
#pragma unroll
  for (int fm = 0; fm < 2; ++fm) {
    int rb = m0 + wr * 32 + fm * 16 + lg * 4;
#pragma unroll
    for (int fn = 0; fn < 4; ++fn) {
      int col = n0 + wc * 64 + fn * 16 + lr;
      float bv = bias[col];
#pragma unroll
      for (int j = 0; j < 4; ++j) {
        int row = rb + j;
        if (row < M) {
          float v = acc[fm][fn][j] + bv;
          if (relu_split) {
            v = fmaxf(v, 0.f);
            unsigned short hv = f2bf(v);
            long long o = (long long)row * N + col;
            Chi[o] = hv;
            Clo[o] = f2bf(v - bf2f(hv));
          } else {
            C[(long long)row * N + col] = v;
          }
        }
      }
    }
  }
}

// ---- LDS-staged GEMM with FUSED residual + LayerNorm + split (N=128 fixed) ----
__global__ __launch_bounds__(256) void k_gemm3_ln(
    const unsigned short* __restrict__ Ah, const unsigned short* __restrict__ Al,
    const unsigned short* __restrict__ Wh, const unsigned short* __restrict__ Wl,
    const float* __restrict__ bias, const float* __restrict__ g,
    const float* __restrict__ be, float* __restrict__ hres,
    unsigned short* __restrict__ hhi, unsigned short* __restrict__ hlo,
    int M, int K) {
  __shared__ unsigned short sAh[64 * 40], sAl[64 * 40];
  __shared__ unsigned short sWh[128 * 40], sWl[128 * 40];
  __shared__ float redS[64][2];
  __shared__ float redQ[64][2];
  const int m0 = blockIdx.x * 64;
  const int tid = threadIdx.x, lane = tid & 63, wid = tid >> 6;
  const int wr = wid >> 1, wc = wid & 1;
  const int lr = lane & 15, lg = lane >> 4;
  f32x4 acc[2][4];
#pragma unroll
  for (int a = 0; a < 2; ++a)
#pragma unroll
    for (int b = 0; b < 4; ++b) acc[a][b] = (f32x4){0.f, 0.f, 0.f, 0.f};
  const int ar = tid >> 2, ak = (tid & 3) * 8;
  const int wrr = tid >> 1, wkk = (tid & 1) * 16;
  const bool a_ok = (m0 + ar) < M;
  const long long a_base = (long long)(m0 + ar) * K + ak;
  const long long w_base = (long long)wrr * K + wkk;  // n0 = 0
  for (int k0 = 0; k0 < K; k0 += 32) {
    u16x8 vah = {0, 0, 0, 0, 0, 0, 0, 0}, val = {0, 0, 0, 0, 0, 0, 0, 0};
    if (a_ok) {
      vah = *(const u16x8*)(Ah + a_base + k0);
      val = *(const u16x8*)(Al + a_base + k0);
    }
    u16x8 vwh0 = *(const u16x8*)(Wh + w_base + k0);
    u16x8 vwh1 = *(const u16x8*)(Wh + w_base + k0 + 8);
    u16x8 vwl0 = *(const u16x8*)(Wl + w_base + k0);
    u16x8 vwl1 = *(const u16x8*)(Wl + w_base + k0 + 8);
    __syncthreads();
    *(u16x8*)&sAh[ar * 40 + ak] = vah;
    *(u16x8*)&sAl[ar * 40 + ak] = val;
    *(u16x8*)&sWh[wrr * 40 + wkk] = vwh0;
    *(u16x8*)&sWh[wrr * 40 + wkk + 8] = vwh1;
    *(u16x8*)&sWl[wrr * 40 + wkk] = vwl0;
    *(u16x8*)&sWl[wrr * 40 + wkk + 8] = vwl1;
    __syncthreads();
    bf16x8 fah[2], fal[2], fwh[4], fwl[4];
#pragma unroll
    for (int fm = 0; fm < 2; ++fm) {
      int o = (wr * 32 + fm * 16 + lr) * 40 + lg * 8;
      fah[fm] = *(const bf16x8*)&sAh[o];
      fal[fm] = *(const bf16x8*)&sAl[o];
    }
#pragma unroll
    for (int fn = 0; fn < 4; ++fn) {
      int o = (wc * 64 + fn * 16 + lr) * 40 + lg * 8;
      fwh[fn] = *(const bf16x8*)&sWh[o];
      fwl[fn] = *(const bf16x8*)&sWl[o];
    }
#pragma unroll
    for (int fm = 0; fm < 2; ++fm)
#pragma unroll
      for (int fn = 0; fn < 4; ++fn) {
        acc[fm][fn] = __builtin_amdgcn_mfma_f32_16x16x32_bf16(
            fah[fm], fwl[fn], acc[fm][fn], 0, 0, 0);
        acc[fm][fn] = __builtin_amdgcn_mfma_f32_16x16x32_bf16(
            fal[fm], fwh[fn], acc[fm][fn], 0, 0, 0);
        acc[fm][fn] = __builtin_amdgcn_mfma_f32_16x16x32_bf16(
            fah[fm], fwh[fn], acc[fm][fn], 0, 0, 0);
      }
  }
  // ---- fused epilogue: x = residual + gemm + bias; row LN over 128 cols ----
  float x[2][4][4];
#pragma unroll
  for (int fm = 0; fm < 2; ++fm)
#pragma unroll
    for (int fn = 0; fn < 4; ++fn) {
      int col = wc * 64 + fn * 16 + lr;
      float bv = bias[col];
#pragma unroll
      for (int j = 0; j < 4; ++j) {
        int row = m0 + wr * 32 + fm * 16 + lg * 4 + j;
        float r = (row < M) ? hres[(long long)row * D + col] : 0.f;
        x[fm][fn][j] = acc[fm][fn][j] + bv + r;
      }
    }
#pragma unroll
  for (int fm = 0; fm < 2; ++fm)
#pragma unroll
    for (int j = 0; j < 4; ++j) {
      float s = x[fm][0][j] + x[fm][1][j] + x[fm][2][j] + x[fm][3][j];
      s += __shfl_xor(s, 1);
      s += __shfl_xor(s, 2);
      s += __shfl_xor(s, 4);
      s += __shfl_xor(s, 8);
      if (lr == 0) redS[wr * 32 + fm * 16 + lg * 4 + j][wc] = s;
    }
  __syncthreads();
  float mean[2][4];
#pragma unroll
  for (int fm = 0; fm < 2; ++fm)
#pragma unroll
    for (int j = 0; j < 4; ++j) {
      int rl = wr * 32 + fm * 16 + lg * 4 + j;
      mean[fm][j] = (redS[rl][0] + redS[rl][1]) * (1.f / 128.f);
      float d0 = x[fm][0][j] - mean[fm][j];
      float d1 = x[fm][1][j] - mean[fm][j];
      float d2 = x[fm][2][j] - mean[fm][j];
      float d3 = x[fm][3][j] - mean[fm][j];
      float q = d0 * d0 + d1 * d1 + d2 * d2 + d3 * d3;
      q += __shfl_xor(q, 1);
      q += __shfl_xor(q, 2);
      q += __shfl_xor(q, 4);
      q += __shfl_xor(q, 8);
      if (lr == 0) redQ[rl][wc] = q;
    }
  __syncthreads();
#pragma unroll
  for (int fm = 0; fm < 2; ++fm)
#pragma unroll
    for (int j = 0; j < 4; ++j) {
      int rl = wr * 32 + fm * 16 + lg * 4 + j;
      int row = m0 + rl;
      if (row >= M) continue;
      float var = (redQ[rl][0] + redQ[rl][1]) * (1.f / 128.f);
      float sd = sqrtf(var + LN_EPS);
#pragma unroll
      for (int fn = 0; fn < 4; ++fn) {
        int col = wc * 64 + fn * 16 + lr;
        float o = (x[fm][fn][j] - mean[fm][j]) / sd * g[col] + be[col];
        long long ix = (long long)row * D + col;
        hres[ix] = o;
        unsigned short t = f2bf(o);
        hhi[ix] = t;
        hlo[ix] = f2bf(o - bf2f(t));
      }
    }
}

// ---- fp32 vector GEMM (batched S = q@k^T, N=100) ----
__global__ __launch_bounds__(256) void k_gemm(
    const float* __restrict__ A, long long sA,
    const float* __restrict__ W, long long sW,
    const float* __restrict__ bias,
    float* __restrict__ C, long long sC,
    int M, int N, int K, float scale, int relu) {
  __shared__ float As[32][72];
  __shared__ float Ws[32][72];
  A += (long long)blockIdx.z * sA;
  W += (long long)blockIdx.z * sW;
  C += (long long)blockIdx.z * sC;
  int m0 = blockIdx.x * 64, n0 = blockIdx.y * 64;
  int tid = threadIdx.x;
  int lx = tid & 31, ly = tid >> 5;
  int tc = tid & 15, tr = tid >> 4;
  float acc[4][4] = {};
  for (int k0 = 0; k0 < K; k0 += 32) {
#pragma unroll
    for (int i = 0; i < 8; ++i) {
      int m = m0 + ly + i * 8;
      As[lx][ly + i * 8] = (m < M) ? A[(long long)m * K + k0 + lx] : 0.f;
      int n = n0 + ly + i * 8;
      Ws[lx][ly + i * 8] = (n < N) ? W[(long long)n * K + k0 + lx] : 0.f;
    }
    __syncthreads();
#pragma unroll
    for (int k = 0; k < 32; ++k) {
      float4 av = *(const float4*)&As[k][tr * 4];
      float4 wv = *(const float4*)&Ws[k][tc * 4];
      const float* ap = (const float*)&av;
      const float* wp = (const float*)&wv;
#pragma unroll
      for (int i = 0; i < 4; ++i)
#pragma unroll
        for (int j = 0; j < 4; ++j)
          acc[i][j] = fmaf(ap[i], wp[j], acc[i][j]);
    }
    __syncthreads();
  }
#pragma unroll
  for (int i = 0; i < 4; ++i) {
    int m = m0 + tr * 4 + i;
    if (m >= M) continue;
#pragma unroll
    for (int j = 0; j < 4; ++j) {
      int n = n0 + tc * 4 + j;
      if (n >= N) continue;
      float v = acc[i][j] * scale;
      if (bias) v += bias[n];
      if (relu) v = fmaxf(v, 0.f);
      C[(long long)m * N + n] = v;
    }
  }
}

// ---------------- attention: 512 thr; swizzled K (kills 8-way conflict);
// float4 PV ----
__global__ __launch_bounds__(512) void k_attn(
    const float* __restrict__ qkv, unsigned short* __restrict__ aoh,
    unsigned short* __restrict__ aol) {
  __shared__ float Qs[NNODE][20];  // linear; reused as softmax scratch
  __shared__ float Ks[NNODE][20];  // block-rotated by (j>>3)&3
  __shared__ float Vs[NNODE][20];  // linear (PV reads are same-k broadcast)
  __shared__ float Ss[NNODE][101];
  int bh = blockIdx.x;
  int b = bh >> 3, hh = bh & 7;
  const float* base = qkv + (long long)b * NNODE * 384 + hh * HD;
  int tid = threadIdx.x;
  for (int idx = tid; idx < NNODE * HD; idx += 512) {
    int n = idx >> 4, d2 = idx & 15;
    float qv = base[(long long)n * 384 + d2];
    float kv = base[(long long)n * 384 + 128 + d2];
    float vv = base[(long long)n * 384 + 256 + d2];
    Qs[n][d2] = qv;
    // K swizzle: logical float4-block (d2>>2) stored at ((d2>>2)+(n>>3))&3
    int kp = ((((d2 >> 2) + (n >> 3)) & 3) << 2) | (d2 & 3);
    Ks[n][kp] = kv;
    Vs[n][d2] = vv;
  }
  __syncthreads();
  for (int p = tid; p < NNODE * NNODE; p += 512) {
    int i = p / 100, j = p - i * 100;
    int rot = (j >> 3) & 3;
    const float4* qv = (const float4*)&Qs[i][0];
    float s = 0.f;
#pragma unroll
    for (int t = 0; t < 4; ++t) {
      float4 q = qv[t];
      float4 k = *(const float4*)&Ks[j][(((t + rot) & 3) << 2)];
      s = fmaf(q.x, k.x, s);
      s = fmaf(q.y, k.y, s);
      s = fmaf(q.z, k.z, s);
      s = fmaf(q.w, k.w, s);
    }
    Ss[i][j] = s * 0.25f; /* hd^-0.5 */
  }
  __syncthreads();
  // parallel softmax: 2 threads/row (Qs dead -> scratch)
  float* red = (float*)Qs;
  int r = tid >> 1, hf = tid & 1;
  float* row = &Ss[r][hf * 50];
  if (tid < 200) {
    float mx = row[0];
    for (int j = 1; j < 50; ++j) mx = fmaxf(mx, row[j]);
    red[tid] = mx;
  }
  __syncthreads();
  if (tid < 200) {
    float mx = fmaxf(red[r * 2], red[r * 2 + 1]);
    float sum = 0.f;
    for (int j = 0; j < 50; ++j) {
      float e = expf(row[j] - mx);
      row[j] = e;
      sum += e;
    }
    red[256 + tid] = sum;
  }
  __syncthreads();
  if (tid < 200) {
    float tot = red[256 + r * 2] + red[256 + r * 2 + 1];
    for (int j = 0; j < 50; ++j) row[j] = row[j] / tot;
  }
  __syncthreads();
  // PV: one float4 of V per thread-output (100 rows x 4 quads = 400 tasks)
  for (int p = tid; p < NNODE * 4; p += 512) {
    int i = p >> 2, q = p & 3;
    float4 o = {0.f, 0.f, 0.f, 0.f};
    for (int k = 0; k < NNODE; ++k) {
      float sv = Ss[i][k];
      float4 v = *(const float4*)&Vs[k][q << 2];
      o.x = fmaf(sv, v.x, o.x);
      o.y = fmaf(sv, v.y, o.y);
      o.z = fmaf(sv, v.z, o.z);
      o.w = fmaf(sv, v.w, o.w);
    }
    long long idx = ((long long)b * NNODE + i) * D + hh * HD + (q << 2);
    const float* op = (const float*)&o;
#pragma unroll
    for (int e = 0; e < 4; ++e) {
      unsigned short hv = f2bf(op[e]);
      aoh[idx + e] = hv;
      aol[idx + e] = f2bf(op[e] - bf2f(hv));
    }
  }
}

// ---------------- greedy decode: one wave per batch element ----------------
__global__ __launch_bounds__(64) void k_decode(
    const float* __restrict__ S, const int* __restrict__ start,
    float* __restrict__ tour, float* __restrict__ logits) {
  __shared__ float Sl[NNODE * NNODE];
  int b = blockIdx.x;
  const float* Sg = S + (long long)b * NNODE * NNODE;
  int l = threadIdx.x;
  for (int i = l; i < NNODE * NNODE; i += 64) Sl[i] = Sg[i];
  __syncthreads();
  unsigned long long visLo = 1ull, visHi = 0ull;
  int node = start[b];
  float* lg = logits + (long long)b * 99 * 100;
  for (int t = 0; t < 99; ++t) {
    if (node < 64) visLo |= 1ull << node;
    else visHi |= 1ull << (node - 64);
    const float* row = &Sl[node * 100];
    float c0 = ((visLo >> l) & 1ull) ? NEGW : row[l];
    float c1 = NEGW;
    int j2 = l + 64;
    if (j2 < NNODE && !((visHi >> l) & 1ull)) c1 = row[j2];
    lg[t * 100 + l] = c0;
    if (j2 < NNODE) lg[t * 100 + j2] = c1;
    if (l == 0) tour[b * 99 + t] = (float)node;
    float v = c0;
    int idx = l;
    if (c1 > v) { v = c1; idx = j2; }
    for (int off = 32; off; off >>= 1) {
      float ov = __shfl_xor(v, off);
      int oi = __shfl_xor(idx, off);
      if (ov > v || (ov == v && oi < idx)) { v = ov; idx = oi; }
    }
    node = idx;
  }
}

extern "C" void kernel_launch(void* const* d_in, const int* in_sizes, int n_in,
                              void* d_out, int out_size, void* d_ws, size_t ws_size,
                              hipStream_t stream) {
  const float* c     = (const float*)d_in[0];
  const int*   start = (const int*)d_in[1];
  const float* w_inp = (const float*)d_in[2];
  const float* b_inp = (const float*)d_in[3];
  const float* wqkv  = (const float*)d_in[4];
  const float* bqkv  = (const float*)d_in[5];
  const float* wo    = (const float*)d_in[6];
  const float* bo    = (const float*)d_in[7];
  const float* w1    = (const float*)d_in[8];
  const float* b1    = (const float*)d_in[9];
  const float* w2    = (const float*)d_in[10];
  const float* b2    = (const float*)d_in[11];
  const float* g1    = (const float*)d_in[12];
  const float* be1   = (const float*)d_in[13];
  const float* g2    = (const float*)d_in[14];
  const float* be2   = (const float*)d_in[15];
  const float* wq    = (const float*)d_in[16];
  const float* bq    = (const float*)d_in[17];
  const float* wk    = (const float*)d_in[18];
  const float* bk    = (const float*)d_in[19];

  // ---- workspace layout (validated R10/R11) ----
  float* h = (float*)d_ws;
  unsigned short* h_hi = (unsigned short*)((char*)d_ws + 26214400);
  unsigned short* h_lo = h_hi + (size_t)M_TOT * D;
  unsigned short* wsp  = (unsigned short*)((char*)d_ws + 52428800);
  unsigned short* wqkvh = wsp;
  unsigned short* wqkvl = wsp + 147456;
  unsigned short* woh   = wsp + 294912;
  unsigned short* wol   = wsp + 344064;
  unsigned short* w1h   = wsp + 393216;
  unsigned short* w1l   = wsp + 1179648;
  unsigned short* w2h   = wsp + 1966080;
  unsigned short* w2l   = wsp + 2752512;
  unsigned short* wqh   = wsp + 3538944;
  unsigned short* wql   = wsp + 3555328;
  unsigned short* wkh   = wsp + 3571712;
  unsigned short* wkl   = wsp + 3588096;
  float* wsArena = (float*)((char*)d_ws + 59637760);
  long long R = (long long)ws_size - 59637760LL;
  if (R < 0) R = 0;

  float* tour   = (float*)d_out;
  float* logits = (float*)d_out + (size_t)BATCH * (NNODE - 1);
  long long LBYTES = (long long)BATCH * (NNODE - 1) * NNODE * 4;

  float* encArena = (R >= LBYTES) ? wsArena : logits;
  long long E = (R >= LBYTES) ? R : LBYTES;

  long long CB = E / 204800;
  if (CB < 1) CB = 1;
  if (CB > BATCH) CB = BATCH;
  long long RB = (E / 8192) & ~3LL;
  if (RB < 4) RB = 4;
  if (RB > M_TOT) RB = M_TOT;
  long long CB2 = R / 142400;
  if (CB2 < 1) CB2 = 1;
  if (CB2 > BATCH) CB2 = BATCH;

  k_split<<<576, 256, 0, stream>>>(wqkv, wqkvh, wqkvl, 147456);
  k_split<<<192, 256, 0, stream>>>(wo, woh, wol, 49152);
  k_split<<<3072, 256, 0, stream>>>(w1, w1h, w1l, 786432);
  k_split<<<3072, 256, 0, stream>>>(w2, w2h, w2l, 786432);
  k_split<<<64, 256, 0, stream>>>(wq, wqh, wql, 16384);
  k_split<<<64, 256, 0, stream>>>(wk, wkh, wkl, 16384);

  k_inproj<<<(M_TOT * D + 255) / 256, 256, 0, stream>>>(c, w_inp, b_inp, h,
                                                        h_hi, h_lo);

  for (int l = 0; l < NL; ++l) {
    unsigned short* wqkvh_l = wqkvh + (size_t)l * 49152;
    unsigned short* wqkvl_l = wqkvl + (size_t)l * 49152;
    unsigned short* woh_l = woh + (size_t)l * 16384;
    unsigned short* wol_l = wol + (size_t)l * 16384;
    unsigned short* w1h_l = w1h + (size_t)l * 262144;
    unsigned short* w1l_l = w1l + (size_t)l * 262144;
    unsigned short* w2h_l = w2h + (size_t)l * 262144;
    unsigned short* w2l_l = w2l + (size_t)l * 262144;
    const float* bqkv_l = bqkv + (size_t)l * 384;
    const float* bo_l = bo + (size_t)l * D;
    const float* b1_l = b1 + (size_t)l * DFF;
    const float* b2_l = b2 + (size_t)l * D;
    const float* g1_l = g1 + (size_t)l * D;
    const float* be1_l = be1 + (size_t)l * D;
    const float* g2_l = g2 + (size_t)l * D;
    const float* be2_l = be2 + (size_t)l * D;

    // ---- attention sublayer (wo-GEMM + residual + LN1 fused) ----
    for (long long b0 = 0; b0 < BATCH; b0 += CB) {
      long long cb = (BATCH - b0 < CB) ? (BATCH - b0) : CB;
      long long rows = cb * NNODE;
      float* qkvbuf = encArena;
      unsigned short* aoh = (unsigned short*)(qkvbuf + rows * 384);
      unsigned short* aol = aoh + rows * D;
      float* hrow = h + b0 * NNODE * D;
      unsigned short* hhir = h_hi + b0 * NNODE * D;
      unsigned short* hlor = h_lo + b0 * NNODE * D;
      k_gemm3<<<dim3((unsigned)((rows + 63) / 64), 3), 256, 0, stream>>>(
          hhir, hlor, wqkvh_l, wqkvl_l, bqkv_l, qkvbuf, nullptr, nullptr,
          (int)rows, 384, D, 0);
      k_attn<<<(unsigned)(cb * NH), 512, 0, stream>>>(qkvbuf, aoh, aol);
      k_gemm3_ln<<<(unsigned)((rows + 63) / 64), 256, 0, stream>>>(
          aoh, aol, woh_l, wol_l, bo_l, g1_l, be1_l, hrow, hhir, hlor,
          (int)rows, D);
    }

    // ---- FFN sublayer (w2-GEMM + residual + LN2 fused) ----
    for (long long r0 = 0; r0 < M_TOT; r0 += RB) {
      long long mr = (M_TOT - r0 < RB) ? (M_TOT - r0) : RB;
      unsigned short* ff1h = (unsigned short*)encArena;
      unsigned short* ff1l = ff1h + mr * DFF;
      float* hrow = h + r0 * D;
      unsigned short* hhir = h_hi + r0 * D;
      unsigned short* hlor = h_lo + r0 * D;
      k_gemm3<<<dim3((unsigned)((mr + 63) / 64), DFF / 128), 256, 0, stream>>>(
          hhir, hlor, w1h_l, w1l_l, b1_l, nullptr, ff1h, ff1l,
          (int)mr, DFF, D, 1);
      k_gemm3_ln<<<(unsigned)((mr + 63) / 64), 256, 0, stream>>>(
          ff1h, ff1l, w2h_l, w2l_l, b2_l, g2_l, be2_l, hrow, hhir, hlor,
          (int)mr, DFF);
    }
  }

  // ---- decode: qp/kp (bf16x3) -> S (fp32) -> greedy ----
  for (long long b0 = 0; b0 < BATCH; b0 += CB2) {
    long long cb = (BATCH - b0 < CB2) ? (BATCH - b0) : CB2;
    long long rows = cb * NNODE;
    float* qp = wsArena;
    float* kp = qp + rows * D;
    float* Sb = kp + rows * D;
    unsigned short* hhir = h_hi + b0 * NNODE * D;
    unsigned short* hlor = h_lo + b0 * NNODE * D;
    k_gemm3<<<dim3((unsigned)((rows + 63) / 64), 1), 256, 0, stream>>>(
        hhir, hlor, wqh, wql, bq, qp, nullptr, nullptr, (int)rows, D, D, 0);
    k_gemm3<<<dim3((unsigned)((rows + 63) / 64), 1), 256, 0, stream>>>(
        hhir, hlor, wkh, wkl, bk, kp, nullptr, nullptr, (int)rows, D, D, 0);
    k_gemm<<<dim3(2, 2, (unsigned)cb), 256, 0, stream>>>(
        qp, (long long)NNODE * D, kp, (long long)NNODE * D, nullptr,
        Sb, (long long)NNODE * NNODE, NNODE, NNODE, D,
        0.08838834764831845f, 0);
    k_decode<<<(unsigned)cb, 64, 0, stream>>>(Sb, start + b0, tour + b0 * 99,
                                              logits + b0 * 99 * 100);
  }
}